// Round 12
// baseline (79.278 us; speedup 1.0000x reference)
//
#include <hip/hip_runtime.h>
#include <math.h>

// Problem geometry
#define T_LEN   160000
#define NROW    128        // 64 rows of x then 64 rows of n
#define CH      32         // samples per chunk
#define NCH     5000       // CH*NCH == T_LEN
#define OWNT    20         // chunks per thread in scan_row (256*20 >= 5000)
#define OWN_W   62         // own chunks per wave in emit (+2 warm = 64)
#define B_OWN   (4 * OWN_W)      // 248 own chunks per block
#define TILES   21               // ceil(5000/248)
#define NBLK    (NROW * TILES)   // 2688

// HP biquad: y = x - 2 x1 + x2 + 1.99599 y1 - 0.996 y2
#define C1_HP ( 1.99599)
#define C2_HP (-0.996)
#define C1F   ( 1.99599f)
#define C2F   (-0.996f)

#define S1_FLOAT2S (NROW * NCH)          // 640000 float2 = 5,120,000 B
#define M2_BYTE_OFF (S1_FLOAT2S * 8)     // 16B-aligned

__device__ __forceinline__ int swzf(int F) { return F ^ ((F >> 3) & 7); }
__device__ __forceinline__ float clip1f(float v) { return fminf(fmaxf(v, -1.0f), 1.0f); }

// ---------------------------------------------------------------------------
// prep: M2 = A2stage^CH for the two random filters (per-filter constant).
// m2[f] = (m00, m01, m10, m11) as float4.
// ---------------------------------------------------------------------------
__global__ void prep_kernel(const float* __restrict__ cx, const float* __restrict__ cn,
                            float4* __restrict__ m2) {
  int f = threadIdx.x;
  if (f >= 2) return;
  const float* c = f ? cn : cx;
  const float A1c = c[0], A2c = c[1];
  float pm2 = 0.f, pm1 = 0.f, p0 = 1.f;
#pragma unroll
  for (int k = 0; k < CH; ++k) {
    float pn = -A1c * p0 - A2c * pm1;
    pm2 = pm1; pm1 = p0; p0 = pn;
  }
  m2[f] = make_float4(p0, -A2c * pm1, pm1, -A2c * pm2);
}

// ---------------------------------------------------------------------------
// pass_a1: per (row, chunk) LOCAL stage-1 end state (zero y-init, true
// x-history). FIR part f32 (inputs exact), y-recurrence f64; e1 stored f32.
// ---------------------------------------------------------------------------
__global__ __launch_bounds__(256) void pass_a1(const float* __restrict__ x,
                                               const float* __restrict__ nn,
                                               float2* __restrict__ e1) {
  int g = blockIdx.x * blockDim.x + threadIdx.x;
  if (g >= NROW * NCH) return;
  int row = g / NCH, c = g % NCH;
  const float* src = (row < 64) ? (x + (size_t)row * T_LEN)
                                : (nn + (size_t)(row - 64) * T_LEN);
  const float* xp = src + c * CH;
  float x1 = 0.f, x2 = 0.f;
  if (c) { x1 = xp[-1]; x2 = xp[-2]; }
  double y1 = 0.0, y2 = 0.0;
#pragma unroll
  for (int j = 0; j < CH; j += 4) {
    float4 xv = *reinterpret_cast<const float4*>(xp + j);
#define A1STEP(XF) { float xt = (XF); \
    float fir = (xt - 2.f * x1 + x2); \
    double y = fma(C1_HP, y1, fma(C2_HP, y2, (double)fir)); \
    x2 = x1; x1 = xt; y2 = y1; y1 = y; }
    A1STEP(xv.x) A1STEP(xv.y) A1STEP(xv.z) A1STEP(xv.w)
#undef A1STEP
  }
  e1[g] = make_float2((float)y1, (float)y2);
}

// ---------------------------------------------------------------------------
// scan_row: one block (4 waves) per row; affine Kogge-Stone over chunk maps
// (f64 internal, f32 e-inputs); emits exact chunk-start states (f32).
// ---------------------------------------------------------------------------
__global__ __launch_bounds__(256) void scan_row(const float2* __restrict__ e,
                                                float2* __restrict__ s) {
  __shared__ double wm[4][6];
  const int t = threadIdx.x, row = blockIdx.x;
  const int lane = t & 63, wv = t >> 6;
  double pm2 = 0.0, pm1 = 0.0, p0 = 1.0;
#pragma unroll
  for (int k = 1; k <= CH; ++k) {
    double pn = C1_HP * p0 + C2_HP * pm1;
    pm2 = pm1; pm1 = p0; p0 = pn;
  }
  const double m00 = p0,  m01 = C2_HP * pm1;
  const double m10 = pm1, m11 = C2_HP * pm2;
  const float2* ep = e + (size_t)row * NCH;
  const int base = t * OWNT;
  double f1 = 0.0, f2 = 0.0;
  for (int j = 0; j < OWNT; ++j) {
    int c = base + j;
    float2 ev = (c < NCH) ? ep[c] : make_float2(0.f, 0.f);
    double n1 = m00 * f1 + m01 * f2 + (double)ev.x;
    double n2 = m10 * f1 + m11 * f2 + (double)ev.y;
    f1 = n1; f2 = n2;
  }
  double b00 = m00, b01 = m01, b10 = m10, b11 = m11;
  double r00 = 1.0, r01 = 0.0, r10 = 0.0, r11 = 1.0;
  int ee = OWNT;
  while (ee) {
    if (ee & 1) {
      double t00 = b00 * r00 + b01 * r10, t01 = b00 * r01 + b01 * r11;
      double t10 = b10 * r00 + b11 * r10, t11 = b10 * r01 + b11 * r11;
      r00 = t00; r01 = t01; r10 = t10; r11 = t11;
    }
    double q00 = b00 * b00 + b01 * b10, q01 = b00 * b01 + b01 * b11;
    double q10 = b10 * b00 + b11 * b10, q11 = b10 * b01 + b11 * b11;
    b00 = q00; b01 = q01; b10 = q10; b11 = q11;
    ee >>= 1;
  }
  double P00 = r00, P01 = r01, P10 = r10, P11 = r11, V1 = f1, V2 = f2;
#pragma unroll
  for (int off = 1; off < 64; off <<= 1) {
    double u00 = __shfl_up(P00, off), u01 = __shfl_up(P01, off);
    double u10 = __shfl_up(P10, off), u11 = __shfl_up(P11, off);
    double uv1 = __shfl_up(V1, off),  uv2 = __shfl_up(V2, off);
    if (lane >= off) {
      double nv1 = P00 * uv1 + P01 * uv2 + V1;
      double nv2 = P10 * uv1 + P11 * uv2 + V2;
      double n00 = P00 * u00 + P01 * u10, n01 = P00 * u01 + P01 * u11;
      double n10 = P10 * u00 + P11 * u10, n11 = P10 * u01 + P11 * u11;
      P00 = n00; P01 = n01; P10 = n10; P11 = n11; V1 = nv1; V2 = nv2;
    }
  }
  if (lane == 63) {
    wm[wv][0] = P00; wm[wv][1] = P01; wm[wv][2] = P10; wm[wv][3] = P11;
    wm[wv][4] = V1;  wm[wv][5] = V2;
  }
  __syncthreads();
  double S1 = 0.0, S2 = 0.0;
  for (int w = 0; w < wv; ++w) {
    double n1 = wm[w][0] * S1 + wm[w][1] * S2 + wm[w][4];
    double n2 = wm[w][2] * S1 + wm[w][3] * S2 + wm[w][5];
    S1 = n1; S2 = n2;
  }
  double q00 = __shfl_up(P00, 1), q01 = __shfl_up(P01, 1);
  double q10 = __shfl_up(P10, 1), q11 = __shfl_up(P11, 1);
  double qv1 = __shfl_up(V1, 1),  qv2 = __shfl_up(V2, 1);
  double st1, st2;
  if (lane == 0) { st1 = S1; st2 = S2; }
  else { st1 = q00 * S1 + q01 * S2 + qv1; st2 = q10 * S1 + q11 * S2 + qv2; }
  float2* sp = s + (size_t)row * NCH;
  double s1v = st1, s2v = st2;
  for (int j = 0; j < OWNT; ++j) {
    int c = base + j;
    if (c < NCH) {
      sp[c] = make_float2((float)s1v, (float)s2v);
      float2 ev = ep[c];
      double n1 = m00 * s1v + m01 * s2v + (double)ev.x;
      double n2 = m10 * s1v + m11 * s2v + (double)ev.y;
      s1v = n1; s2v = n2;
    }
  }
}

// ---------------------------------------------------------------------------
// emit: per-WAVE tiles (2 warm + 62 own chunks); lane owns one chunk.
// Coalesced load -> per-wave LDS region (one barrier). FIR precomputed in
// registers (input-only); then 1-fma/sample y-chain and z-chain (reassociated
// fmaf); e2 via shfl_up; s2 = e2[c-1] + M2*e2[c-2] (M2 from prep);
// 1-fma/sample homogeneous correction + clip; direct 128B global stores.
// ---------------------------------------------------------------------------
__global__ __launch_bounds__(256, 5) void emit_kernel(const float* __restrict__ x,
                                                      const float* __restrict__ nn,
                                                      const float2* __restrict__ s1,
                                                      const float* __restrict__ cx,
                                                      const float* __restrict__ cn,
                                                      const float4* __restrict__ m2,
                                                      float* __restrict__ out) {
  __shared__ float4 ws4[2048];                 // 4 waves x 512 float4 = 32 KB
  const int tid = threadIdx.x, lane = tid & 63, wv = tid >> 6;
  const int b = blockIdx.x;
  const int row = b / TILES, tile = b % TILES;
  const int wave_c0 = tile * B_OWN + wv * OWN_W;   // first own chunk of wave
  const int cb = wave_c0 - 2 + lane;               // this lane's chunk
  const float* src = (row < 64) ? x + (size_t)row * T_LEN
                                : nn + (size_t)(row - 64) * T_LEN;
  const float2* srow = s1 + (size_t)row * NCH;
  const float* cf = (row < 64) ? cx : cn;
  const float A1c = cf[0], A2c = cf[1], B1c = cf[2], B2c = cf[3];
  const float4 M2 = m2[(row < 64) ? 0 : 1];

  // ---- coalesced load of the wave's 64-chunk tile ----
  const int WOFF = wv * 512;
  const long base4 = (long)(wave_c0 - 2) * 8;      // float4 units
#pragma unroll
  for (int q = 0; q < 8; ++q) {
    int f = q * 64 + lane;
    long g4 = base4 + f;
    float4 v = make_float4(0.f, 0.f, 0.f, 0.f);
    if (g4 >= 0 && g4 < (long)NCH * 8)
      v = reinterpret_cast<const float4*>(src)[g4];
    ws4[WOFF + swzf(f)] = v;
  }
  __syncthreads();

  const bool valid = (cb >= 0) && (cb < NCH);
  float4 a[8];
#pragma unroll
  for (int q = 0; q < 8; ++q) a[q] = ws4[WOFF + swzf(lane * 8 + q)];

  // x-tail of previous chunk from previous lane (lane 0: global read)
  float tx = __shfl_up(a[7].w, 1);
  float ty = __shfl_up(a[7].z, 1);

  float x1, x2, y1, y2, v1, v2;
  if (valid && cb > 0) {
    float2 sv = srow[cb];
    y1 = sv.x; y2 = sv.y;
    v1 = clip1f(sv.x); v2 = clip1f(sv.y);
    if (lane == 0) {
      float2 tp = *reinterpret_cast<const float2*>(src + (long)cb * CH - 2);
      x2 = tp.x; x1 = tp.y;
    } else { x1 = tx; x2 = ty; }
  } else { x1 = 0.f; x2 = 0.f; y1 = 0.f; y2 = 0.f; v1 = 0.f; v2 = 0.f; }

  // ---- FIR precompute (input-only, fully parallel): a[q] := fir ----
  {
    float xp1 = x1, xp2 = x2;
#pragma unroll
    for (int q = 0; q < 8; ++q) {
      float4 t = a[q];
      float4 f;
      f.x = t.x - 2.f * xp1 + xp2;
      f.y = t.y - 2.f * t.x + xp1;
      f.z = t.z - 2.f * t.y + t.x;
      f.w = t.w - 2.f * t.z + t.y;
      xp2 = t.z; xp1 = t.w;
      a[q] = f;
    }
  }

  // ---- fused stage1 + stage2(zero-z), 1-fma/sample chains: a[q] := zb ----
  float z1 = 0.f, z2 = 0.f;
  if (valid) {
#define AB(REF) { \
    float yy = fmaf(C1F, y1, fmaf(C2F, y2, (REF))); \
    float vv = clip1f(yy); \
    float zz = fmaf(-A1c, z1, fmaf(-A2c, z2, fmaf(B2c, v2, fmaf(B1c, v1, vv)))); \
    y2 = y1; y1 = yy; v2 = v1; v1 = vv; z2 = z1; z1 = zz; REF = zz; }
#pragma unroll
    for (int q = 0; q < 8; ++q) { AB(a[q].x) AB(a[q].y) AB(a[q].z) AB(a[q].w) }
#undef AB
  }

  // e2 states of the two previous chunks via shuffles
  float u1x = __shfl_up(z1, 1), u1y = __shfl_up(z2, 1);
  float u2x = __shfl_up(z1, 2), u2y = __shfl_up(z2, 2);

  // ---- correction + clip + direct store (own lanes only) ----
  if (lane >= 2 && valid) {
    float s2x, s2y;
    if (cb == 0)      { s2x = 0.f; s2y = 0.f; }
    else if (cb == 1) { s2x = u1x; s2y = u1y; }
    else {
      s2x = fmaf(M2.x, u2x, fmaf(M2.y, u2y, u1x));
      s2y = fmaf(M2.z, u2x, fmaf(M2.w, u2y, u1y));
    }
    float h1 = s2x, h2 = s2y;
    float* op = out + (size_t)row * T_LEN + (long)cb * CH;
#define CS(ZB, OT) { float hh = fmaf(-A1c, h1, -A2c * h2); \
    OT = clip1f((ZB) + hh); h2 = h1; h1 = hh; }
#pragma unroll
    for (int q = 0; q < 8; ++q) {
      float4 o;
      CS(a[q].x, o.x) CS(a[q].y, o.y) CS(a[q].z, o.z) CS(a[q].w, o.w)
      *reinterpret_cast<float4*>(op + 4 * q) = o;
    }
#undef CS
  }
}

// ---------------------------------------------------------------------------
extern "C" void kernel_launch(void* const* d_in, const int* in_sizes, int n_in,
                              void* d_out, int out_size, void* d_ws, size_t ws_size,
                              hipStream_t stream) {
  const float* x  = (const float*)d_in[0];   // (64, 160000)
  const float* nn = (const float*)d_in[1];   // (64, 160000)
  const float* cx = (const float*)d_in[2];   // (4,) a1,a2,b1,b2
  const float* cn = (const float*)d_in[3];   // (4,)
  float* out = (float*)d_out;                // (128, 160000) flat

  // e1 (f32, 5.12 MB) aliases d_out: written by pass_a1, consumed by
  // scan_row, then fully overwritten by emit. s1 + m2 in ws.
  float2* e1 = (float2*)d_out;
  float2* s1 = (float2*)d_ws;
  float4* m2 = (float4*)((char*)d_ws + M2_BYTE_OFF);

  const int total = NROW * NCH;              // 640000
  const int blk = 256;
  const int nb = (total + blk - 1) / blk;    // 2500

  prep_kernel<<<1, 64, 0, stream>>>(cx, cn, m2);
  pass_a1<<<nb, blk, 0, stream>>>(x, nn, e1);
  scan_row<<<NROW, blk, 0, stream>>>(e1, s1);
  emit_kernel<<<NBLK, blk, 0, stream>>>(x, nn, s1, cx, cn, m2, out);
}

// Round 13
// 61.739 us; speedup vs baseline: 1.2841x; 1.2841x over previous
//
#include <hip/hip_runtime.h>
#include <math.h>

// Problem geometry
#define T_LEN   160000
#define NROW    128        // 64 rows of x then 64 rows of n
#define CH      32         // samples per chunk
#define NCH     5000       // CH*NCH == T_LEN
#define OWNT    20         // chunks per thread in scan_row (256*20 >= 5000)
#define OWN_W   62         // own chunks per wave in emit (+2 warm = 64)
#define B_OWN   (4 * OWN_W)      // 248 own chunks per block
#define TILES   21               // ceil(5000/248)
#define NBLK    (NROW * TILES)   // 2688

// HP biquad: y = x - 2 x1 + x2 + 1.99599 y1 - 0.996 y2
#define C1_HP ( 1.99599)
#define C2_HP (-0.996)
#define C1F   ( 1.99599f)
#define C2F   (-0.996f)

#define S1_FLOAT2S (NROW * NCH)          // 640000 float2 = 5,120,000 B
#define M2_BYTE_OFF (S1_FLOAT2S * 8)     // 16B-aligned

__device__ __forceinline__ int swzf(int F) { return F ^ ((F >> 3) & 7); }
__device__ __forceinline__ float clip1f(float v) { return fminf(fmaxf(v, -1.0f), 1.0f); }

// ---------------------------------------------------------------------------
// pass_a1: per (row, chunk) LOCAL stage-1 end state (zero y-init, true
// x-history). FIR f32, y-recurrence f64; e1 stored f32.
// Block 0, threads 0/1 additionally emit M2 = A2stage^CH per filter.
// ---------------------------------------------------------------------------
__global__ __launch_bounds__(256) void pass_a1(const float* __restrict__ x,
                                               const float* __restrict__ nn,
                                               float2* __restrict__ e1,
                                               const float* __restrict__ cx,
                                               const float* __restrict__ cn,
                                               float4* __restrict__ m2) {
  int g = blockIdx.x * blockDim.x + threadIdx.x;
  if (g < 2) {                       // fold former prep_kernel
    const float* c = g ? cn : cx;
    const float A1c = c[0], A2c = c[1];
    float pm2 = 0.f, pm1 = 0.f, p0 = 1.f;
#pragma unroll
    for (int k = 0; k < CH; ++k) {
      float pn = -A1c * p0 - A2c * pm1;
      pm2 = pm1; pm1 = p0; p0 = pn;
    }
    m2[g] = make_float4(p0, -A2c * pm1, pm1, -A2c * pm2);
  }
  if (g >= NROW * NCH) return;
  int row = g / NCH, c = g % NCH;
  const float* src = (row < 64) ? (x + (size_t)row * T_LEN)
                                : (nn + (size_t)(row - 64) * T_LEN);
  const float* xp = src + c * CH;
  float x1 = 0.f, x2 = 0.f;
  if (c) { x1 = xp[-1]; x2 = xp[-2]; }
  double y1 = 0.0, y2 = 0.0;
#pragma unroll
  for (int j = 0; j < CH; j += 4) {
    float4 xv = *reinterpret_cast<const float4*>(xp + j);
#define A1STEP(XF) { float xt = (XF); \
    float fir = (xt - 2.f * x1 + x2); \
    double y = fma(C1_HP, y1, fma(C2_HP, y2, (double)fir)); \
    x2 = x1; x1 = xt; y2 = y1; y1 = y; }
    A1STEP(xv.x) A1STEP(xv.y) A1STEP(xv.z) A1STEP(xv.w)
#undef A1STEP
  }
  e1[g] = make_float2((float)y1, (float)y2);
}

// ---------------------------------------------------------------------------
// scan_row: one block (4 waves) per row; affine Kogge-Stone over chunk maps
// (f64 internal, f32 e-inputs); emits exact chunk-start states (f32).
// ---------------------------------------------------------------------------
__global__ __launch_bounds__(256) void scan_row(const float2* __restrict__ e,
                                                float2* __restrict__ s) {
  __shared__ double wm[4][6];
  const int t = threadIdx.x, row = blockIdx.x;
  const int lane = t & 63, wv = t >> 6;
  double pm2 = 0.0, pm1 = 0.0, p0 = 1.0;
#pragma unroll
  for (int k = 1; k <= CH; ++k) {
    double pn = C1_HP * p0 + C2_HP * pm1;
    pm2 = pm1; pm1 = p0; p0 = pn;
  }
  const double m00 = p0,  m01 = C2_HP * pm1;
  const double m10 = pm1, m11 = C2_HP * pm2;
  const float2* ep = e + (size_t)row * NCH;
  const int base = t * OWNT;
  double f1 = 0.0, f2 = 0.0;
  for (int j = 0; j < OWNT; ++j) {
    int c = base + j;
    float2 ev = (c < NCH) ? ep[c] : make_float2(0.f, 0.f);
    double n1 = m00 * f1 + m01 * f2 + (double)ev.x;
    double n2 = m10 * f1 + m11 * f2 + (double)ev.y;
    f1 = n1; f2 = n2;
  }
  double b00 = m00, b01 = m01, b10 = m10, b11 = m11;
  double r00 = 1.0, r01 = 0.0, r10 = 0.0, r11 = 1.0;
  int ee = OWNT;
  while (ee) {
    if (ee & 1) {
      double t00 = b00 * r00 + b01 * r10, t01 = b00 * r01 + b01 * r11;
      double t10 = b10 * r00 + b11 * r10, t11 = b10 * r01 + b11 * r11;
      r00 = t00; r01 = t01; r10 = t10; r11 = t11;
    }
    double q00 = b00 * b00 + b01 * b10, q01 = b00 * b01 + b01 * b11;
    double q10 = b10 * b00 + b11 * b10, q11 = b10 * b01 + b11 * b11;
    b00 = q00; b01 = q01; b10 = q10; b11 = q11;
    ee >>= 1;
  }
  double P00 = r00, P01 = r01, P10 = r10, P11 = r11, V1 = f1, V2 = f2;
#pragma unroll
  for (int off = 1; off < 64; off <<= 1) {
    double u00 = __shfl_up(P00, off), u01 = __shfl_up(P01, off);
    double u10 = __shfl_up(P10, off), u11 = __shfl_up(P11, off);
    double uv1 = __shfl_up(V1, off),  uv2 = __shfl_up(V2, off);
    if (lane >= off) {
      double nv1 = P00 * uv1 + P01 * uv2 + V1;
      double nv2 = P10 * uv1 + P11 * uv2 + V2;
      double n00 = P00 * u00 + P01 * u10, n01 = P00 * u01 + P01 * u11;
      double n10 = P10 * u00 + P11 * u10, n11 = P10 * u01 + P11 * u11;
      P00 = n00; P01 = n01; P10 = n10; P11 = n11; V1 = nv1; V2 = nv2;
    }
  }
  if (lane == 63) {
    wm[wv][0] = P00; wm[wv][1] = P01; wm[wv][2] = P10; wm[wv][3] = P11;
    wm[wv][4] = V1;  wm[wv][5] = V2;
  }
  __syncthreads();
  double S1 = 0.0, S2 = 0.0;
  for (int w = 0; w < wv; ++w) {
    double n1 = wm[w][0] * S1 + wm[w][1] * S2 + wm[w][4];
    double n2 = wm[w][2] * S1 + wm[w][3] * S2 + wm[w][5];
    S1 = n1; S2 = n2;
  }
  double q00 = __shfl_up(P00, 1), q01 = __shfl_up(P01, 1);
  double q10 = __shfl_up(P10, 1), q11 = __shfl_up(P11, 1);
  double qv1 = __shfl_up(V1, 1),  qv2 = __shfl_up(V2, 1);
  double st1, st2;
  if (lane == 0) { st1 = S1; st2 = S2; }
  else { st1 = q00 * S1 + q01 * S2 + qv1; st2 = q10 * S1 + q11 * S2 + qv2; }
  float2* sp = s + (size_t)row * NCH;
  double s1v = st1, s2v = st2;
  for (int j = 0; j < OWNT; ++j) {
    int c = base + j;
    if (c < NCH) {
      sp[c] = make_float2((float)s1v, (float)s2v);
      float2 ev = ep[c];
      double n1 = m00 * s1v + m01 * s2v + (double)ev.x;
      double n2 = m10 * s1v + m11 * s2v + (double)ev.y;
      s1v = n1; s2v = n2;
    }
  }
}

// ---------------------------------------------------------------------------
// emit: per-WAVE tiles (2 warm + 62 own chunks); lane owns one chunk.
// ZERO barriers (all exchange wave-local: own LDS region + shfl).
// load (coalesced, global->LDS) -> ds_read per-chunk -> FIR -> fused
// stage1+stage2(zero-z) -> shfl e2 -> s2 = e2[c-1]+M2*e2[c-2] -> homogeneous
// correction + clip -> ds_write back -> coalesced LDS->global store.
// ---------------------------------------------------------------------------
__global__ __launch_bounds__(256, 5) void emit_kernel(const float* __restrict__ x,
                                                      const float* __restrict__ nn,
                                                      const float2* __restrict__ s1,
                                                      const float* __restrict__ cx,
                                                      const float* __restrict__ cn,
                                                      const float4* __restrict__ m2,
                                                      float* __restrict__ out) {
  __shared__ float4 ws4[2048];                 // 4 waves x 512 float4 = 32 KB
  const int tid = threadIdx.x, lane = tid & 63, wv = tid >> 6;
  const int b = blockIdx.x;
  const int row = b / TILES, tile = b % TILES;
  const int wave_c0 = tile * B_OWN + wv * OWN_W;   // first own chunk of wave
  const int cb = wave_c0 - 2 + lane;               // this lane's chunk
  const float* src = (row < 64) ? x + (size_t)row * T_LEN
                                : nn + (size_t)(row - 64) * T_LEN;
  const float2* srow = s1 + (size_t)row * NCH;
  const float* cf = (row < 64) ? cx : cn;
  const float A1c = cf[0], A2c = cf[1], B1c = cf[2], B2c = cf[3];
  const float4 M2 = m2[(row < 64) ? 0 : 1];
  const bool valid = (cb >= 0) && (cb < NCH);

  // seed loads issued early (overlap with LDS staging)
  float sy1 = 0.f, sy2 = 0.f;
  if (valid && cb > 0) { float2 sv = srow[cb]; sy1 = sv.x; sy2 = sv.y; }
  float t0x = 0.f, t0y = 0.f;
  if (lane == 0 && valid && cb > 0) {
    float2 tp = *reinterpret_cast<const float2*>(src + (long)cb * CH - 2);
    t0y = tp.x; t0x = tp.y;           // x1 = tp.y, x2 = tp.x
  }

  // ---- per-wave coalesced load of the 64-chunk tile (no barrier) ----
  const int WOFF = wv * 512;
  const long base4 = (long)(wave_c0 - 2) * 8;      // float4 units
#pragma unroll
  for (int q = 0; q < 8; ++q) {
    int f = q * 64 + lane;
    long g4 = base4 + f;
    float4 v = make_float4(0.f, 0.f, 0.f, 0.f);
    if (g4 >= 0 && g4 < (long)NCH * 8)
      v = reinterpret_cast<const float4*>(src)[g4];
    ws4[WOFF + swzf(f)] = v;
  }

  float4 a[8];
#pragma unroll
  for (int q = 0; q < 8; ++q) a[q] = ws4[WOFF + swzf(lane * 8 + q)];

  // x-tail of previous chunk from previous lane (lane 0: global)
  float tx = __shfl_up(a[7].w, 1);
  float ty = __shfl_up(a[7].z, 1);

  float x1, x2, y1, y2, v1, v2;
  if (valid && cb > 0) {
    y1 = sy1; y2 = sy2;
    v1 = clip1f(sy1); v2 = clip1f(sy2);
    if (lane == 0) { x1 = t0x; x2 = t0y; }
    else { x1 = tx; x2 = ty; }
  } else { x1 = 0.f; x2 = 0.f; y1 = 0.f; y2 = 0.f; v1 = 0.f; v2 = 0.f; }

  // ---- FIR precompute (input-only, parallel): a[q] := fir ----
  {
    float xp1 = x1, xp2 = x2;
#pragma unroll
    for (int q = 0; q < 8; ++q) {
      float4 t = a[q];
      float4 f;
      f.x = t.x - 2.f * xp1 + xp2;
      f.y = t.y - 2.f * t.x + xp1;
      f.z = t.z - 2.f * t.y + t.x;
      f.w = t.w - 2.f * t.z + t.y;
      xp2 = t.z; xp1 = t.w;
      a[q] = f;
    }
  }

  // ---- fused stage1 + stage2(zero-z), 1-fma/sample chains: a[q] := zb ----
  float z1 = 0.f, z2 = 0.f;
  if (valid) {
#define AB(REF) { \
    float yy = fmaf(C1F, y1, fmaf(C2F, y2, (REF))); \
    float vv = clip1f(yy); \
    float zz = fmaf(-A1c, z1, fmaf(-A2c, z2, fmaf(B2c, v2, fmaf(B1c, v1, vv)))); \
    y2 = y1; y1 = yy; v2 = v1; v1 = vv; z2 = z1; z1 = zz; REF = zz; }
#pragma unroll
    for (int q = 0; q < 8; ++q) { AB(a[q].x) AB(a[q].y) AB(a[q].z) AB(a[q].w) }
#undef AB
  }

  // e2 states of the two previous chunks via shuffles
  float u1x = __shfl_up(z1, 1), u1y = __shfl_up(z2, 1);
  float u2x = __shfl_up(z1, 2), u2y = __shfl_up(z2, 2);

  // ---- correction + clip, write back to LDS (own lanes only) ----
  if (lane >= 2 && valid) {
    float s2x, s2y;
    if (cb == 0)      { s2x = 0.f; s2y = 0.f; }
    else if (cb == 1) { s2x = u1x; s2y = u1y; }
    else {
      s2x = fmaf(M2.x, u2x, fmaf(M2.y, u2y, u1x));
      s2y = fmaf(M2.z, u2x, fmaf(M2.w, u2y, u1y));
    }
    float h1 = s2x, h2 = s2y;
#define CS(ZB, OT) { float hh = fmaf(-A1c, h1, -A2c * h2); \
    OT = clip1f((ZB) + hh); h2 = h1; h1 = hh; }
#pragma unroll
    for (int q = 0; q < 8; ++q) {
      float4 o;
      CS(a[q].x, o.x) CS(a[q].y, o.y) CS(a[q].z, o.z) CS(a[q].w, o.w)
      ws4[WOFF + swzf(lane * 8 + q)] = o;
    }
#undef CS
  }

  // ---- coalesced store of own chunks (f >= 16) from LDS (no barrier) ----
  float* orow = out + (size_t)row * T_LEN;
#pragma unroll
  for (int q = 0; q < 8; ++q) {
    int f = q * 64 + lane;
    long g4 = base4 + f;
    if (f >= 16 && g4 < (long)NCH * 8)
      reinterpret_cast<float4*>(orow)[g4] = ws4[WOFF + swzf(f)];
  }
}

// ---------------------------------------------------------------------------
extern "C" void kernel_launch(void* const* d_in, const int* in_sizes, int n_in,
                              void* d_out, int out_size, void* d_ws, size_t ws_size,
                              hipStream_t stream) {
  const float* x  = (const float*)d_in[0];   // (64, 160000)
  const float* nn = (const float*)d_in[1];   // (64, 160000)
  const float* cx = (const float*)d_in[2];   // (4,) a1,a2,b1,b2
  const float* cn = (const float*)d_in[3];   // (4,)
  float* out = (float*)d_out;                // (128, 160000) flat

  // e1 (f32, 5.12 MB) aliases d_out: written by pass_a1, consumed by
  // scan_row, then fully overwritten by emit. s1 + m2 in ws.
  float2* e1 = (float2*)d_out;
  float2* s1 = (float2*)d_ws;
  float4* m2 = (float4*)((char*)d_ws + M2_BYTE_OFF);

  const int total = NROW * NCH;              // 640000
  const int blk = 256;
  const int nb = (total + blk - 1) / blk;    // 2500

  pass_a1<<<nb, blk, 0, stream>>>(x, nn, e1, cx, cn, m2);
  scan_row<<<NROW, blk, 0, stream>>>(e1, s1);
  emit_kernel<<<NBLK, blk, 0, stream>>>(x, nn, s1, cx, cn, m2, out);
}

// Round 14
// 60.037 us; speedup vs baseline: 1.3205x; 1.0283x over previous
//
#include <hip/hip_runtime.h>
#include <math.h>

// Problem geometry
#define T_LEN   160000
#define NROW    128        // 64 rows of x then 64 rows of n
#define CH      32         // samples per chunk
#define NCH     5000       // CH*NCH == T_LEN
#define OWNT    20         // chunks per thread in scan_row (256*20 >= 5000)
#define OWN_W   62         // own chunks per wave in emit (+2 warm = 64)
#define B_OWN   (4 * OWN_W)      // 248 own chunks per block
#define TILES   21               // ceil(5000/248)
#define NBLK    (NROW * TILES)   // 2688

// HP biquad: y = x - 2 x1 + x2 + 1.99599 y1 - 0.996 y2
#define C1_HP ( 1.99599)
#define C2_HP (-0.996)
#define C1F   ( 1.99599f)
#define C2F   (-0.996f)

#define S1_FLOAT2S (NROW * NCH)          // 640000 float2 = 5,120,000 B
#define M2_BYTE_OFF (S1_FLOAT2S * 8)     // 16B-aligned

#define GLOBAL_AS __attribute__((address_space(1)))
#define SHARED_AS __attribute__((address_space(3)))

__device__ __forceinline__ int swzf(int F) { return F ^ ((F >> 3) & 7); }
__device__ __forceinline__ float clip1f(float v) { return fminf(fmaxf(v, -1.0f), 1.0f); }

// ---------------------------------------------------------------------------
// pass_a1: per (row, chunk) LOCAL stage-1 end state (zero y-init, true
// x-history). FIR f32, y-recurrence f64; e1 stored f32.
// Block 0, threads 0/1 additionally emit M2 = A2stage^CH per filter.
// ---------------------------------------------------------------------------
__global__ __launch_bounds__(256) void pass_a1(const float* __restrict__ x,
                                               const float* __restrict__ nn,
                                               float2* __restrict__ e1,
                                               const float* __restrict__ cx,
                                               const float* __restrict__ cn,
                                               float4* __restrict__ m2) {
  int g = blockIdx.x * blockDim.x + threadIdx.x;
  if (g < 2) {                       // fold former prep_kernel
    const float* c = g ? cn : cx;
    const float A1c = c[0], A2c = c[1];
    float pm2 = 0.f, pm1 = 0.f, p0 = 1.f;
#pragma unroll
    for (int k = 0; k < CH; ++k) {
      float pn = -A1c * p0 - A2c * pm1;
      pm2 = pm1; pm1 = p0; p0 = pn;
    }
    m2[g] = make_float4(p0, -A2c * pm1, pm1, -A2c * pm2);
  }
  if (g >= NROW * NCH) return;
  int row = g / NCH, c = g % NCH;
  const float* src = (row < 64) ? (x + (size_t)row * T_LEN)
                                : (nn + (size_t)(row - 64) * T_LEN);
  const float* xp = src + c * CH;
  float x1 = 0.f, x2 = 0.f;
  if (c) { x1 = xp[-1]; x2 = xp[-2]; }
  double y1 = 0.0, y2 = 0.0;
#pragma unroll
  for (int j = 0; j < CH; j += 4) {
    float4 xv = *reinterpret_cast<const float4*>(xp + j);
#define A1STEP(XF) { float xt = (XF); \
    float fir = (xt - 2.f * x1 + x2); \
    double y = fma(C1_HP, y1, fma(C2_HP, y2, (double)fir)); \
    x2 = x1; x1 = xt; y2 = y1; y1 = y; }
    A1STEP(xv.x) A1STEP(xv.y) A1STEP(xv.z) A1STEP(xv.w)
#undef A1STEP
  }
  e1[g] = make_float2((float)y1, (float)y2);
}

// ---------------------------------------------------------------------------
// scan_row: one block (4 waves) per row; affine Kogge-Stone over chunk maps
// (f64 internal, f32 e-inputs); emits exact chunk-start states (f32).
// ---------------------------------------------------------------------------
__global__ __launch_bounds__(256) void scan_row(const float2* __restrict__ e,
                                                float2* __restrict__ s) {
  __shared__ double wm[4][6];
  const int t = threadIdx.x, row = blockIdx.x;
  const int lane = t & 63, wv = t >> 6;
  double pm2 = 0.0, pm1 = 0.0, p0 = 1.0;
#pragma unroll
  for (int k = 1; k <= CH; ++k) {
    double pn = C1_HP * p0 + C2_HP * pm1;
    pm2 = pm1; pm1 = p0; p0 = pn;
  }
  const double m00 = p0,  m01 = C2_HP * pm1;
  const double m10 = pm1, m11 = C2_HP * pm2;
  const float2* ep = e + (size_t)row * NCH;
  const int base = t * OWNT;
  double f1 = 0.0, f2 = 0.0;
  for (int j = 0; j < OWNT; ++j) {
    int c = base + j;
    float2 ev = (c < NCH) ? ep[c] : make_float2(0.f, 0.f);
    double n1 = m00 * f1 + m01 * f2 + (double)ev.x;
    double n2 = m10 * f1 + m11 * f2 + (double)ev.y;
    f1 = n1; f2 = n2;
  }
  double b00 = m00, b01 = m01, b10 = m10, b11 = m11;
  double r00 = 1.0, r01 = 0.0, r10 = 0.0, r11 = 1.0;
  int ee = OWNT;
  while (ee) {
    if (ee & 1) {
      double t00 = b00 * r00 + b01 * r10, t01 = b00 * r01 + b01 * r11;
      double t10 = b10 * r00 + b11 * r10, t11 = b10 * r01 + b11 * r11;
      r00 = t00; r01 = t01; r10 = t10; r11 = t11;
    }
    double q00 = b00 * b00 + b01 * b10, q01 = b00 * b01 + b01 * b11;
    double q10 = b10 * b00 + b11 * b10, q11 = b10 * b01 + b11 * b11;
    b00 = q00; b01 = q01; b10 = q10; b11 = q11;
    ee >>= 1;
  }
  double P00 = r00, P01 = r01, P10 = r10, P11 = r11, V1 = f1, V2 = f2;
#pragma unroll
  for (int off = 1; off < 64; off <<= 1) {
    double u00 = __shfl_up(P00, off), u01 = __shfl_up(P01, off);
    double u10 = __shfl_up(P10, off), u11 = __shfl_up(P11, off);
    double uv1 = __shfl_up(V1, off),  uv2 = __shfl_up(V2, off);
    if (lane >= off) {
      double nv1 = P00 * uv1 + P01 * uv2 + V1;
      double nv2 = P10 * uv1 + P11 * uv2 + V2;
      double n00 = P00 * u00 + P01 * u10, n01 = P00 * u01 + P01 * u11;
      double n10 = P10 * u00 + P11 * u10, n11 = P10 * u01 + P11 * u11;
      P00 = n00; P01 = n01; P10 = n10; P11 = n11; V1 = nv1; V2 = nv2;
    }
  }
  if (lane == 63) {
    wm[wv][0] = P00; wm[wv][1] = P01; wm[wv][2] = P10; wm[wv][3] = P11;
    wm[wv][4] = V1;  wm[wv][5] = V2;
  }
  __syncthreads();
  double S1 = 0.0, S2 = 0.0;
  for (int w = 0; w < wv; ++w) {
    double n1 = wm[w][0] * S1 + wm[w][1] * S2 + wm[w][4];
    double n2 = wm[w][2] * S1 + wm[w][3] * S2 + wm[w][5];
    S1 = n1; S2 = n2;
  }
  double q00 = __shfl_up(P00, 1), q01 = __shfl_up(P01, 1);
  double q10 = __shfl_up(P10, 1), q11 = __shfl_up(P11, 1);
  double qv1 = __shfl_up(V1, 1),  qv2 = __shfl_up(V2, 1);
  double st1, st2;
  if (lane == 0) { st1 = S1; st2 = S2; }
  else { st1 = q00 * S1 + q01 * S2 + qv1; st2 = q10 * S1 + q11 * S2 + qv2; }
  float2* sp = s + (size_t)row * NCH;
  double s1v = st1, s2v = st2;
  for (int j = 0; j < OWNT; ++j) {
    int c = base + j;
    if (c < NCH) {
      sp[c] = make_float2((float)s1v, (float)s2v);
      float2 ev = ep[c];
      double n1 = m00 * s1v + m01 * s2v + (double)ev.x;
      double n2 = m10 * s1v + m11 * s2v + (double)ev.y;
      s1v = n1; s2v = n2;
    }
  }
}

// ---------------------------------------------------------------------------
// emit: per-WAVE tiles (2 warm + 62 own chunks); lane owns one chunk.
// ZERO barriers. Interior tiles stage x via async global_load_lds (width 16,
// linear LDS dest, swizzle applied to the GLOBAL source index — swzf is an
// involution so the layout matches the manual path exactly). Boundary tiles
// (tile 0 / last) use the manual bounds-checked path.
// Then: ds_read per-chunk -> FIR -> fused stage1+stage2(zero-z) -> shfl e2 ->
// s2 = e2[c-1]+M2*e2[c-2] -> homogeneous correction + clip -> ds_write back
// -> coalesced LDS->global store.
// ---------------------------------------------------------------------------
__global__ __launch_bounds__(256, 5) void emit_kernel(const float* __restrict__ x,
                                                      const float* __restrict__ nn,
                                                      const float2* __restrict__ s1,
                                                      const float* __restrict__ cx,
                                                      const float* __restrict__ cn,
                                                      const float4* __restrict__ m2,
                                                      float* __restrict__ out) {
  __shared__ float4 ws4[2048];                 // 4 waves x 512 float4 = 32 KB
  const int tid = threadIdx.x, lane = tid & 63, wv = tid >> 6;
  const int b = blockIdx.x;
  const int row = b / TILES, tile = b % TILES;
  const int wave_c0 = tile * B_OWN + wv * OWN_W;   // first own chunk of wave
  const int cb = wave_c0 - 2 + lane;               // this lane's chunk
  const float* src = (row < 64) ? x + (size_t)row * T_LEN
                                : nn + (size_t)(row - 64) * T_LEN;
  const float4* src4 = reinterpret_cast<const float4*>(src);
  const float2* srow = s1 + (size_t)row * NCH;
  const float* cf = (row < 64) ? cx : cn;
  const float A1c = cf[0], A2c = cf[1], B1c = cf[2], B2c = cf[3];
  const float4 M2 = m2[(row < 64) ? 0 : 1];
  const bool valid = (cb >= 0) && (cb < NCH);

  // seed loads issued early (overlap with LDS staging)
  float sy1 = 0.f, sy2 = 0.f;
  if (valid && cb > 0) { float2 sv = srow[cb]; sy1 = sv.x; sy2 = sv.y; }
  float t0x = 0.f, t0y = 0.f;
  if (lane == 0 && valid && cb > 0) {
    float2 tp = *reinterpret_cast<const float2*>(src + (long)cb * CH - 2);
    t0y = tp.x; t0x = tp.y;           // x1 = tp.y, x2 = tp.x
  }

  const int WOFF = wv * 512;
  const long base4 = (long)(wave_c0 - 2) * 8;      // float4 units
  const bool interior = (base4 >= 0) && (base4 + 512 <= (long)NCH * 8);

  if (interior) {
    // ---- async staging: LDS linear, swizzle folded into global src idx ----
    const int lane_swz = lane ^ ((lane >> 3) & 7);
#pragma unroll
    for (int q = 0; q < 8; ++q) {
      const float4* gp = src4 + base4 + q * 64 + lane_swz;
      __builtin_amdgcn_global_load_lds(
          (const GLOBAL_AS void*)gp,
          (SHARED_AS void*)(ws4 + WOFF + q * 64),
          16, 0, 0);
    }
    asm volatile("s_waitcnt vmcnt(0)" ::: "memory");
  } else {
    // ---- manual bounds-checked staging (identical LDS layout) ----
#pragma unroll
    for (int q = 0; q < 8; ++q) {
      int f = q * 64 + lane;
      long g4 = base4 + f;
      float4 v = make_float4(0.f, 0.f, 0.f, 0.f);
      if (g4 >= 0 && g4 < (long)NCH * 8)
        v = src4[g4];
      ws4[WOFF + swzf(f)] = v;
    }
  }

  float4 a[8];
#pragma unroll
  for (int q = 0; q < 8; ++q) a[q] = ws4[WOFF + swzf(lane * 8 + q)];

  // x-tail of previous chunk from previous lane (lane 0: global)
  float tx = __shfl_up(a[7].w, 1);
  float ty = __shfl_up(a[7].z, 1);

  float x1, x2, y1, y2, v1, v2;
  if (valid && cb > 0) {
    y1 = sy1; y2 = sy2;
    v1 = clip1f(sy1); v2 = clip1f(sy2);
    if (lane == 0) { x1 = t0x; x2 = t0y; }
    else { x1 = tx; x2 = ty; }
  } else { x1 = 0.f; x2 = 0.f; y1 = 0.f; y2 = 0.f; v1 = 0.f; v2 = 0.f; }

  // ---- FIR precompute (input-only, parallel): a[q] := fir ----
  {
    float xp1 = x1, xp2 = x2;
#pragma unroll
    for (int q = 0; q < 8; ++q) {
      float4 t = a[q];
      float4 f;
      f.x = t.x - 2.f * xp1 + xp2;
      f.y = t.y - 2.f * t.x + xp1;
      f.z = t.z - 2.f * t.y + t.x;
      f.w = t.w - 2.f * t.z + t.y;
      xp2 = t.z; xp1 = t.w;
      a[q] = f;
    }
  }

  // ---- fused stage1 + stage2(zero-z), 1-fma/sample chains: a[q] := zb ----
  float z1 = 0.f, z2 = 0.f;
  if (valid) {
#define AB(REF) { \
    float yy = fmaf(C1F, y1, fmaf(C2F, y2, (REF))); \
    float vv = clip1f(yy); \
    float zz = fmaf(-A1c, z1, fmaf(-A2c, z2, fmaf(B2c, v2, fmaf(B1c, v1, vv)))); \
    y2 = y1; y1 = yy; v2 = v1; v1 = vv; z2 = z1; z1 = zz; REF = zz; }
#pragma unroll
    for (int q = 0; q < 8; ++q) { AB(a[q].x) AB(a[q].y) AB(a[q].z) AB(a[q].w) }
#undef AB
  }

  // e2 states of the two previous chunks via shuffles
  float u1x = __shfl_up(z1, 1), u1y = __shfl_up(z2, 1);
  float u2x = __shfl_up(z1, 2), u2y = __shfl_up(z2, 2);

  // ---- correction + clip, write back to LDS (own lanes only) ----
  if (lane >= 2 && valid) {
    float s2x, s2y;
    if (cb == 0)      { s2x = 0.f; s2y = 0.f; }
    else if (cb == 1) { s2x = u1x; s2y = u1y; }
    else {
      s2x = fmaf(M2.x, u2x, fmaf(M2.y, u2y, u1x));
      s2y = fmaf(M2.z, u2x, fmaf(M2.w, u2y, u1y));
    }
    float h1 = s2x, h2 = s2y;
#define CS(ZB, OT) { float hh = fmaf(-A1c, h1, -A2c * h2); \
    OT = clip1f((ZB) + hh); h2 = h1; h1 = hh; }
#pragma unroll
    for (int q = 0; q < 8; ++q) {
      float4 o;
      CS(a[q].x, o.x) CS(a[q].y, o.y) CS(a[q].z, o.z) CS(a[q].w, o.w)
      ws4[WOFF + swzf(lane * 8 + q)] = o;
    }
#undef CS
  }

  // ---- coalesced store of own chunks (f >= 16) from LDS (no barrier) ----
  float* orow = out + (size_t)row * T_LEN;
#pragma unroll
  for (int q = 0; q < 8; ++q) {
    int f = q * 64 + lane;
    long g4 = base4 + f;
    if (f >= 16 && g4 < (long)NCH * 8)
      reinterpret_cast<float4*>(orow)[g4] = ws4[WOFF + swzf(f)];
  }
}

// ---------------------------------------------------------------------------
extern "C" void kernel_launch(void* const* d_in, const int* in_sizes, int n_in,
                              void* d_out, int out_size, void* d_ws, size_t ws_size,
                              hipStream_t stream) {
  const float* x  = (const float*)d_in[0];   // (64, 160000)
  const float* nn = (const float*)d_in[1];   // (64, 160000)
  const float* cx = (const float*)d_in[2];   // (4,) a1,a2,b1,b2
  const float* cn = (const float*)d_in[3];   // (4,)
  float* out = (float*)d_out;                // (128, 160000) flat

  // e1 (f32, 5.12 MB) aliases d_out: written by pass_a1, consumed by
  // scan_row, then fully overwritten by emit. s1 + m2 in ws.
  float2* e1 = (float2*)d_out;
  float2* s1 = (float2*)d_ws;
  float4* m2 = (float4*)((char*)d_ws + M2_BYTE_OFF);

  const int total = NROW * NCH;              // 640000
  const int blk = 256;
  const int nb = (total + blk - 1) / blk;    // 2500

  pass_a1<<<nb, blk, 0, stream>>>(x, nn, e1, cx, cn, m2);
  scan_row<<<NROW, blk, 0, stream>>>(e1, s1);
  emit_kernel<<<NBLK, blk, 0, stream>>>(x, nn, s1, cx, cn, m2, out);
}